// Round 12
// baseline (247.697 us; speedup 1.0000x reference)
//
#include <hip/hip_runtime.h>

// ---------------------------------------------------------------------------
// GCN regressor: 2x GraphConv(norm='both') + ReLU, per-graph mean, linear.
// N=100000 nodes, E=1.6M edges, F=HID=128, G=1024 graphs.
//
// Round 12: persistent grid-stride SpMM (grid = 2048 = 8 blocks/CU cap).
// r10/r11 data: gather rate scales with occupancy (24%->2.05, 32%->2.43,
// 43%->2.78 TB/s) -> still MLP-limited; 6250-block launch churn capped
// occupancy at 43%. Persistent blocks keep all wave slots full.
// Everything else = round 11 (best: 231.8us).
// ---------------------------------------------------------------------------

#define RANGE 256   // nodes per bucket (power of 2; local id fits 8 bits)
#define NBMAX 1024  // max buckets supported (N <= 262144)
#define EPB 4096    // edges per partition block
#define CAP 5120    // padded slots per bucket (mean 4092, sigma 64 -> 16 sigma)

typedef __attribute__((ext_vector_type(4))) float facc4;
typedef __attribute__((ext_vector_type(8))) short bfrag8;

__device__ inline unsigned short f2bf(float x) {  // RNE, finite inputs
  unsigned u = __float_as_uint(x);
  u += 0x7FFFu + ((u >> 16) & 1u);
  return (unsigned short)(u >> 16);
}
__device__ inline float bf2f(unsigned short b) {
  return __uint_as_float((unsigned)b << 16);
}
__device__ inline float bflo(unsigned u) { return __uint_as_float(u << 16); }
__device__ inline float bfhi(unsigned u) { return __uint_as_float(u & 0xFFFF0000u); }

__device__ inline void acc8(float* a, const uint4 v) {
  a[0] += bflo(v.x); a[1] += bfhi(v.x);
  a[2] += bflo(v.y); a[3] += bfhi(v.y);
  a[4] += bflo(v.z); a[5] += bfhi(v.z);
  a[6] += bflo(v.w); a[7] += bfhi(v.w);
}

// gather-accumulate one node's in-edges (8 bf16 feats @ fo) into acc[8]
__device__ inline void gather_node(const int* __restrict__ esrc,
                                   const unsigned short* __restrict__ Y,
                                   int beg, int end, int fo, float* acc) {
  int e = beg;
  for (; e < end && (e & 3); ++e) {
    const uint4 v = *(const uint4*)(Y + (size_t)esrc[e] * 128 + fo);
    acc8(acc, v);
  }
  for (; e + 8 <= end; e += 8) {  // 8 gathers in flight
    const int4 s0 = *(const int4*)(esrc + e);
    const int4 s1 = *(const int4*)(esrc + e + 4);
    const uint4 v0 = *(const uint4*)(Y + (size_t)s0.x * 128 + fo);
    const uint4 v1 = *(const uint4*)(Y + (size_t)s0.y * 128 + fo);
    const uint4 v2 = *(const uint4*)(Y + (size_t)s0.z * 128 + fo);
    const uint4 v3 = *(const uint4*)(Y + (size_t)s0.w * 128 + fo);
    const uint4 v4 = *(const uint4*)(Y + (size_t)s1.x * 128 + fo);
    const uint4 v5 = *(const uint4*)(Y + (size_t)s1.y * 128 + fo);
    const uint4 v6 = *(const uint4*)(Y + (size_t)s1.z * 128 + fo);
    const uint4 v7 = *(const uint4*)(Y + (size_t)s1.w * 128 + fo);
    acc8(acc, v0); acc8(acc, v1); acc8(acc, v2); acc8(acc, v3);
    acc8(acc, v4); acc8(acc, v5); acc8(acc, v6); acc8(acc, v7);
  }
  if (e + 4 <= end) {
    const int4 s0 = *(const int4*)(esrc + e);
    const uint4 v0 = *(const uint4*)(Y + (size_t)s0.x * 128 + fo);
    const uint4 v1 = *(const uint4*)(Y + (size_t)s0.y * 128 + fo);
    const uint4 v2 = *(const uint4*)(Y + (size_t)s0.z * 128 + fo);
    const uint4 v3 = *(const uint4*)(Y + (size_t)s0.w * 128 + fo);
    acc8(acc, v0); acc8(acc, v1); acc8(acc, v2); acc8(acc, v3);
    e += 4;
  }
  for (; e < end; ++e) {
    const uint4 v = *(const uint4*)(Y + (size_t)esrc[e] * 128 + fo);
    acc8(acc, v);
  }
}

// ---- P1: partition edges into fixed-capacity buckets ----------------------
// Two passes over (L2-hot) src/dst with int4 loads; LDS holds only the
// histograms/cursors (8KB). outS: src&255 ; outD: (dst&255)<<24 | src.
__global__ __launch_bounds__(256) void k_part(const int* __restrict__ src,
                                              const int* __restrict__ dst,
                                              int* __restrict__ curS,
                                              int* __restrict__ curD,
                                              unsigned char* __restrict__ outS,
                                              unsigned int* __restrict__ outD,
                                              int E, int NB) {
  __shared__ int hS[NBMAX];  // 4KB
  __shared__ int hD[NBMAX];  // 4KB
  const int t = threadIdx.x;
  for (int i = t; i < NB; i += 256) { hS[i] = 0; hD[i] = 0; }
  __syncthreads();
  const int e0 = blockIdx.x * EPB;
  #pragma unroll
  for (int i = 0; i < EPB / 1024; ++i) {
    const int e = e0 + (i * 256 + t) * 4;
    if (e + 3 < E) {
      const int4 s4 = *(const int4*)(src + e);
      const int4 d4 = *(const int4*)(dst + e);
      atomicAdd(&hS[s4.x >> 8], 1); atomicAdd(&hS[s4.y >> 8], 1);
      atomicAdd(&hS[s4.z >> 8], 1); atomicAdd(&hS[s4.w >> 8], 1);
      atomicAdd(&hD[d4.x >> 8], 1); atomicAdd(&hD[d4.y >> 8], 1);
      atomicAdd(&hD[d4.z >> 8], 1); atomicAdd(&hD[d4.w >> 8], 1);
    } else {
      for (int j = 0; j < 4; ++j) {
        if (e + j < E) {
          atomicAdd(&hS[src[e + j] >> 8], 1);
          atomicAdd(&hD[dst[e + j] >> 8], 1);
        }
      }
    }
  }
  __syncthreads();
  for (int i = t; i < NB; i += 256) {  // reserve chunks; hS/hD become cursors
    int c = hS[i];
    hS[i] = c ? atomicAdd(&curS[i], c) : 0;
    c = hD[i];
    hD[i] = c ? atomicAdd(&curD[i], c) : 0;
  }
  __syncthreads();
  #pragma unroll
  for (int i = 0; i < EPB / 1024; ++i) {
    const int e = e0 + (i * 256 + t) * 4;
    if (e + 3 < E) {
      const int4 s4 = *(const int4*)(src + e);
      const int4 d4 = *(const int4*)(dst + e);
      const int sv[4] = {s4.x, s4.y, s4.z, s4.w};
      const int dv[4] = {d4.x, d4.y, d4.z, d4.w};
      #pragma unroll
      for (int j = 0; j < 4; ++j) {
        int p = atomicAdd(&hS[sv[j] >> 8], 1);
        if (p < CAP)
          outS[(size_t)(sv[j] >> 8) * CAP + p] = (unsigned char)(sv[j] & 255);
        p = atomicAdd(&hD[dv[j] >> 8], 1);
        if (p < CAP)
          outD[(size_t)(dv[j] >> 8) * CAP + p] =
              ((unsigned)(dv[j] & 255) << 24) | (unsigned)sv[j];
      }
    } else {
      for (int j = 0; j < 4; ++j) {
        if (e + j < E) {
          const int sv = src[e + j], dv = dst[e + j];
          int p = atomicAdd(&hS[sv >> 8], 1);
          if (p < CAP)
            outS[(size_t)(sv >> 8) * CAP + p] = (unsigned char)(sv & 255);
          p = atomicAdd(&hD[dv >> 8], 1);
          if (p < CAP)
            outD[(size_t)(dv >> 8) * CAP + p] =
                ((unsigned)(dv & 255) << 24) | (unsigned)sv;
        }
      }
    }
  }
}

// ---- merged prep: [0,NB) CSR+cD ; [NB,2NB) out-deg+cS ; gstart ; gsum=0 ;
//      W split/pack (both layers). -------------------------------------------
// W frag order: idx = ((kc*8+nb)*64 + lane)*8 + i  <-  W[k][n],
// k = kc*32 + (lane>>4)*8 + i, n = nb*16 + (lane&15). W2 frags at +16384.
__global__ __launch_bounds__(256) void k_prep(
    const unsigned int* __restrict__ outD, const int* __restrict__ curD,
    int2* __restrict__ rng, int* __restrict__ esrc, float* __restrict__ cD,
    const unsigned char* __restrict__ outS, const int* __restrict__ curS,
    float* __restrict__ cS, const int* __restrict__ gid,
    int* __restrict__ gstart, float* __restrict__ gsum,
    const float* __restrict__ W1, const float* __restrict__ W2,
    unsigned short* __restrict__ Whi, unsigned short* __restrict__ Wlo,
    int N, int NB, int G, int nbN, int nbG) {
  __shared__ int hist[RANGE];
  __shared__ int scn[RANGE];
  const int b = blockIdx.x;
  const int t = threadIdx.x;

  if (b < NB) {  // ---- CSR build + in-degree + cD ----
    const int beg = b * CAP;
    const int cnt = min(curD[b], CAP);
    hist[t] = 0;
    __syncthreads();
    for (int e = t; e < cnt; e += 256)
      atomicAdd(&hist[outD[beg + e] >> 24], 1);
    __syncthreads();
    const int deg = hist[t];
    scn[t] = deg;
    __syncthreads();
    #pragma unroll
    for (int o = 1; o < RANGE; o <<= 1) {
      int u = (t >= o) ? scn[t - o] : 0;
      __syncthreads();
      scn[t] += u;
      __syncthreads();
    }
    const int excl = scn[t] - deg;
    const int node = b * RANGE + t;
    if (node < N) {
      cD[node] = rsqrtf((float)(deg > 1 ? deg : 1));
      rng[node] = make_int2(beg + excl, beg + excl + deg);
    }
    scn[t] = excl;  // becomes the scatter cursor
    __syncthreads();
    for (int e = t; e < cnt; e += 256) {
      const unsigned w = outD[beg + e];
      const int pos = beg + atomicAdd(&scn[w >> 24], 1);
      esrc[pos] = (int)(w & 0x1FFFFu);
    }
  } else if (b < 2 * NB) {  // ---- out-degree -> cS ----
    const int bb = b - NB;
    const int beg = bb * CAP;
    const int cnt = min(curS[bb], CAP);
    hist[t] = 0;
    __syncthreads();
    for (int e = t; e < cnt; e += 256)
      atomicAdd(&hist[outS[beg + e]], 1);
    __syncthreads();
    const int node = bb * RANGE + t;
    if (node < N) cS[node] = rsqrtf((float)(hist[t] > 1 ? hist[t] : 1));
  } else if (b < 2 * NB + nbN) {  // ---- graph starts from sorted gid ----
    const int i = (b - 2 * NB) * 256 + t;
    if (i < N) {
      const int g = gid[i];
      if (i == 0) {
        for (int q = 0; q <= g; ++q) gstart[q] = 0;
      } else {
        const int gp = gid[i - 1];
        for (int q = gp + 1; q <= g; ++q) gstart[q] = i;
      }
      if (i == N - 1) {
        for (int q = g + 1; q <= G; ++q) gstart[q] = N;
      }
    }
  } else if (b < 2 * NB + nbN + nbG) {  // ---- zero gsum ----
    const int i = (b - 2 * NB - nbN) * 256 + t;
    if (i < G) gsum[i] = 0.f;
  } else {  // ---- W split/pack ----
    const int g = (b - 2 * NB - nbN - nbG) * 256 + t;  // 0..32767
    const float* W = (g < 16384) ? W1 : W2;
    const int idx = g & 16383;
    const int i = idx & 7;
    const int l = (idx >> 3) & 63;
    const int nb = (idx >> 9) & 7;
    const int kc = idx >> 12;
    const int k = kc * 32 + ((l >> 4) << 3) + i;
    const int n = (nb << 4) + (l & 15);
    const float v = W[k * 128 + n];
    const unsigned short hi = f2bf(v);
    Whi[g] = hi;
    Wlo[g] = f2bf(v - bf2f(hi));
  }
}

// ---- MFMA GEMM: Y[N,128](bf16) = transform(X) @ W, split-bf16 -------------
// MODE 0: A'[r][k] = Xf[r][k] * cS[r]                      (fp32 input)
// MODE 1: A'[r][k] = relu(Xb[r][k]*cD[r] + bias[k]) * cS[r] (bf16 input)
// 4 waves/block, 16 rows/wave, no LDS. 96 MFMAs (16x16x32 bf16) per wave.
template <int MODE>
__global__ __launch_bounds__(256) void k_mgemm(const float* __restrict__ Xf,
                                               const unsigned short* __restrict__ Xb,
                                               const unsigned short* __restrict__ Whi,
                                               const unsigned short* __restrict__ Wlo,
                                               const float* __restrict__ cS,
                                               const float* __restrict__ cD,
                                               const float* __restrict__ bias,
                                               unsigned short* __restrict__ Y,
                                               int N) {
  const int t = threadIdx.x;
  const int wv = t >> 6;
  const int l = t & 63;
  const int lm = l & 15;
  const int lg = l >> 4;
  const int row0 = (blockIdx.x * 4 + wv) * 16;
  const int row = row0 + lm;
  const bool rv = row < N;
  const int rc = rv ? row : 0;
  const float csr = rv ? cS[rc] : 0.f;  // 0 -> A row = 0
  const float cdr = (MODE == 1) ? (rv ? cD[rc] : 0.f) : 0.f;

  facc4 acc[8];
  #pragma unroll
  for (int nb = 0; nb < 8; ++nb) acc[nb] = (facc4){0.f, 0.f, 0.f, 0.f};

  #pragma unroll
  for (int kc = 0; kc < 4; ++kc) {
    const int k0 = kc * 32 + (lg << 3);
    float a[8];
    if constexpr (MODE == 0) {
      const float4 x0 = *(const float4*)(Xf + (size_t)rc * 128 + k0);
      const float4 x1 = *(const float4*)(Xf + (size_t)rc * 128 + k0 + 4);
      a[0] = x0.x; a[1] = x0.y; a[2] = x0.z; a[3] = x0.w;
      a[4] = x1.x; a[5] = x1.y; a[6] = x1.z; a[7] = x1.w;
      #pragma unroll
      for (int i = 0; i < 8; ++i) a[i] *= csr;
    } else {
      const uint4 xb = *(const uint4*)(Xb + (size_t)rc * 128 + k0);
      a[0] = bflo(xb.x); a[1] = bfhi(xb.x);
      a[2] = bflo(xb.y); a[3] = bfhi(xb.y);
      a[4] = bflo(xb.z); a[5] = bfhi(xb.z);
      a[6] = bflo(xb.w); a[7] = bfhi(xb.w);
      const float4 b0 = *(const float4*)(bias + k0);
      const float4 b1 = *(const float4*)(bias + k0 + 4);
      const float bb[8] = {b0.x, b0.y, b0.z, b0.w, b1.x, b1.y, b1.z, b1.w};
      #pragma unroll
      for (int i = 0; i < 8; ++i)
        a[i] = fmaxf(fmaf(a[i], cdr, bb[i]), 0.f) * csr;
    }
    bfrag8 ah, al;
    #pragma unroll
    for (int i = 0; i < 8; ++i) {
      const unsigned short hh = f2bf(a[i]);
      ah[i] = (short)hh;
      al[i] = (short)f2bf(a[i] - bf2f(hh));
    }
    const size_t kb = ((size_t)kc * 8) * 512 + (size_t)l * 8;
    #pragma unroll
    for (int nb = 0; nb < 8; ++nb) {
      const bfrag8 bh = *(const bfrag8*)(Whi + kb + (size_t)nb * 512);
      const bfrag8 bl = *(const bfrag8*)(Wlo + kb + (size_t)nb * 512);
      acc[nb] = __builtin_amdgcn_mfma_f32_16x16x32_bf16(ah, bh, acc[nb], 0, 0, 0);
      acc[nb] = __builtin_amdgcn_mfma_f32_16x16x32_bf16(ah, bl, acc[nb], 0, 0, 0);
      acc[nb] = __builtin_amdgcn_mfma_f32_16x16x32_bf16(al, bh, acc[nb], 0, 0, 0);
    }
  }

  // C/D layout: col = lane&15, row_in_tile = (lane>>4)*4 + j
  #pragma unroll
  for (int j = 0; j < 4; ++j) {
    const int r = row0 + (lg << 2) + j;
    if (r < N) {
      #pragma unroll
      for (int nb = 0; nb < 8; ++nb)
        Y[(size_t)r * 128 + (nb << 4) + lm] = f2bf(acc[nb][j]);
    }
  }
}

// ---- CSR SpMM over bf16 Y, fp32 accumulate, PERSISTENT grid-stride ---------
// 16 lanes/node (uint4 = 16B/lane), 8-deep gather unroll. Grid = 2048 blocks
// (8/CU residency cap) looping over node-groups: keeps all wave slots full.
// MODE 0: aggb[d] = bf16(sum). MODE 1: fused readout (dot + graph sums).
template <int MODE>
__global__ __launch_bounds__(256) void k_spmm(const int2* __restrict__ rng,
                                              const int* __restrict__ esrc,
                                              const unsigned short* __restrict__ Y,
                                              unsigned short* __restrict__ aggb,
                                              const float* __restrict__ cD,
                                              const float* __restrict__ b2,
                                              const float* __restrict__ fcw,
                                              const int* __restrict__ gid,
                                              float* __restrict__ gsum, int N) {
  __shared__ float sVal[16];
  __shared__ int sGid[16];
  const int t = threadIdx.x;
  const int lane = t & 15;   // 16 lanes per node
  const int grp = t >> 4;    // 0..15
  const int fo = lane * 8;   // feature offset (8 elems = 16B per lane)
  const int ngrp = (N + 15) >> 4;

  for (int gblk = blockIdx.x; gblk < ngrp; gblk += gridDim.x) {
    const int node = gblk * 16 + grp;

    float acc[8] = {0.f, 0.f, 0.f, 0.f, 0.f, 0.f, 0.f, 0.f};
    if (node < N) {
      const int2 be = rng[node];
      gather_node(esrc, Y, be.x, be.y, fo, acc);
    }

    if constexpr (MODE == 0) {
      if (node < N) {
        uint4 w;
        w.x = (unsigned)f2bf(acc[0]) | ((unsigned)f2bf(acc[1]) << 16);
        w.y = (unsigned)f2bf(acc[2]) | ((unsigned)f2bf(acc[3]) << 16);
        w.z = (unsigned)f2bf(acc[4]) | ((unsigned)f2bf(acc[5]) << 16);
        w.w = (unsigned)f2bf(acc[6]) | ((unsigned)f2bf(acc[7]) << 16);
        *(uint4*)(aggb + (size_t)node * 128 + fo) = w;
      }
    } else {
      float s = 0.f;
      if (node < N) {
        const float c = cD[node];
        const float4 bA = *(const float4*)(b2 + fo);
        const float4 bB = *(const float4*)(b2 + fo + 4);
        const float4 wA = *(const float4*)(fcw + fo);
        const float4 wB = *(const float4*)(fcw + fo + 4);
        s += fmaxf(fmaf(acc[0], c, bA.x), 0.f) * wA.x;
        s += fmaxf(fmaf(acc[1], c, bA.y), 0.f) * wA.y;
        s += fmaxf(fmaf(acc[2], c, bA.z), 0.f) * wA.z;
        s += fmaxf(fmaf(acc[3], c, bA.w), 0.f) * wA.w;
        s += fmaxf(fmaf(acc[4], c, bB.x), 0.f) * wB.x;
        s += fmaxf(fmaf(acc[5], c, bB.y), 0.f) * wB.y;
        s += fmaxf(fmaf(acc[6], c, bB.z), 0.f) * wB.z;
        s += fmaxf(fmaf(acc[7], c, bB.w), 0.f) * wB.w;
      }
      #pragma unroll
      for (int o = 8; o > 0; o >>= 1) s += __shfl_down(s, o, 16);
      if (lane == 0) {
        sVal[grp] = (node < N) ? s : 0.f;
        sGid[grp] = (node < N) ? gid[node] : -1;
      }
      __syncthreads();
      if (t == 0) {  // run-combine 16 sorted entries -> few atomics/block
        int cg = -1;
        float cs = 0.f;
        #pragma unroll
        for (int k = 0; k < 16; ++k) {
          const int g = sGid[k];
          if (g < 0) continue;
          if (g == cg) {
            cs += sVal[k];
          } else {
            if (cg >= 0) atomicAdd(&gsum[cg], cs);
            cg = g;
            cs = sVal[k];
          }
        }
        if (cg >= 0) atomicAdd(&gsum[cg], cs);
      }
      __syncthreads();  // protect sVal/sGid before next iteration overwrites
    }
  }
}

__global__ __launch_bounds__(256) void k_final(const float* __restrict__ gsum,
                                               const int* __restrict__ gstart,
                                               const float* __restrict__ fcb,
                                               float* __restrict__ out, int G) {
  const int g = blockIdx.x * 256 + threadIdx.x;
  if (g < G) {
    const int cnt = gstart[g + 1] - gstart[g];
    out[g] = gsum[g] / fmaxf((float)cnt, 1.f) + fcb[0];
  }
}

// ---------------------------------------------------------------------------
extern "C" void kernel_launch(void* const* d_in, const int* in_sizes, int n_in,
                              void* d_out, int out_size, void* d_ws, size_t ws_size,
                              hipStream_t stream) {
  const float* h   = (const float*)d_in[0];
  const int*   src = (const int*)d_in[1];
  const int*   dst = (const int*)d_in[2];
  const int*   gid = (const int*)d_in[3];
  const float* W1  = (const float*)d_in[5];
  const float* b1  = (const float*)d_in[6];
  const float* W2  = (const float*)d_in[7];
  const float* b2  = (const float*)d_in[8];
  const float* fcw = (const float*)d_in[9];
  const float* fcb = (const float*)d_in[10];
  float* out = (float*)d_out;

  const int N = in_sizes[0] / 128;
  const int E = in_sizes[1];
  const int G = out_size;
  const int NB = (N + RANGE - 1) / RANGE;

  char* base = (char*)d_ws;
  size_t off = 0;
  auto alloc = [&](size_t bytes) -> void* {
    void* p = base + off;
    off += (bytes + 1023) & ~(size_t)1023;
    return p;
  };
  unsigned short* Y    = (unsigned short*)alloc((size_t)N * 128 * 2);  // 25.6MB
  unsigned short* aggb = (unsigned short*)alloc((size_t)N * 128 * 2);  // 25.6MB
  // padded bucket arrays alias into aggb (dead before spmm<0> writes aggb)
  unsigned int*  outD = (unsigned int*)aggb;                         // NB*CAP*4
  unsigned char* outS = (unsigned char*)aggb + (size_t)NB * CAP * 4; // NB*CAP
  float* cS     = (float*)alloc((size_t)N * 4);
  float* cD     = (float*)alloc((size_t)N * 4);
  int2*  rng    = (int2*)alloc((size_t)N * 8);
  int*   esrc   = (int*)alloc((size_t)NB * CAP * 4);   // 8MB padded
  int*   cur    = (int*)alloc((size_t)2 * NBMAX * 4);  // curS | curD
  float* gsum   = (float*)alloc((size_t)G * 4);
  int*   gstart = (int*)alloc((size_t)(G + 1) * 4);
  unsigned short* Whi = (unsigned short*)alloc(32768 * 2);  // W1 | W2 frags
  unsigned short* Wlo = (unsigned short*)alloc(32768 * 2);
  (void)ws_size; (void)n_in;

  hipMemsetAsync(cur, 0, (size_t)2 * NBMAX * 4, stream);

  const int nbP = (E + EPB - 1) / EPB;
  const int nbN = (N + 255) / 256;
  const int nbG = (G + 255) / 256;
  k_part<<<nbP, 256, 0, stream>>>(src, dst, cur, cur + NBMAX, outS, outD, E, NB);
  k_prep<<<2 * NB + nbN + nbG + 128, 256, 0, stream>>>(
      outD, cur + NBMAX, rng, esrc, cD, outS, cur, cS, gid, gstart, gsum,
      W1, W2, Whi, Wlo, N, NB, G, nbN, nbG);

  const int nbM = (N + 63) / 64;                 // 64 rows per block
  const int ngrp = (N + 15) / 16;                // spmm node-groups
  const int nbS = ngrp < 2048 ? ngrp : 2048;     // persistent: 8 blocks/CU cap
  // layer 1: Y = (h * cS) @ W1 ; aggb = bf16(SpMM(Y))
  k_mgemm<0><<<nbM, 256, 0, stream>>>(h, (const unsigned short*)nullptr, Whi,
                                      Wlo, cS, cD, b1, Y, N);
  k_spmm<0><<<nbS, 256, 0, stream>>>(rng, esrc, Y, aggb, cD, b2, fcw, gid,
                                     gsum, N);
  // layer 2: Y = (relu(aggb*cD + b1) * cS) @ W2  (in-place Y reuse) ; readout
  k_mgemm<1><<<nbM, 256, 0, stream>>>((const float*)nullptr, aggb, Whi + 16384,
                                      Wlo + 16384, cS, cD, b1, Y, N);
  k_spmm<1><<<nbS, 256, 0, stream>>>(rng, esrc, Y, aggb, cD, b2, fcw, gid,
                                     gsum, N);
  k_final<<<nbG, 256, 0, stream>>>(gsum, gstart, fcb, out, G);
}

// Round 13
// 231.278 us; speedup vs baseline: 1.0710x; 1.0710x over previous
//
#include <hip/hip_runtime.h>

// ---------------------------------------------------------------------------
// GCN regressor: 2x GraphConv(norm='both') + ReLU, per-graph mean, linear.
// N=100000 nodes, E=1.6M edges, F=HID=128, G=1024 graphs.
//
// Round 13: revert r12 persistent grid (regressed 65->77us). NEW: CSR build
// sorts each node's edge list by src-range (key = dstLocal*16 + src>>13,
// 4096-counter LDS scan). deg~16 ~ #ranges -> lists ~src-sorted; all blocks
// sweep src low->high in lockstep -> instantaneous gather working set ~2-6MB
// (L2-hot) instead of 25.6MB -> Y rows fetched ~once instead of ~7x.
// ---------------------------------------------------------------------------

#define RANGE 256   // nodes per bucket (power of 2; local id fits 8 bits)
#define NBMAX 1024  // max buckets supported (N <= 262144)
#define EPB 4096    // edges per partition block
#define CAP 5120    // padded slots per bucket (mean 4092, sigma 64 -> 16 sigma)

typedef __attribute__((ext_vector_type(4))) float facc4;
typedef __attribute__((ext_vector_type(8))) short bfrag8;

__device__ inline unsigned short f2bf(float x) {  // RNE, finite inputs
  unsigned u = __float_as_uint(x);
  u += 0x7FFFu + ((u >> 16) & 1u);
  return (unsigned short)(u >> 16);
}
__device__ inline float bf2f(unsigned short b) {
  return __uint_as_float((unsigned)b << 16);
}
__device__ inline float bflo(unsigned u) { return __uint_as_float(u << 16); }
__device__ inline float bfhi(unsigned u) { return __uint_as_float(u & 0xFFFF0000u); }

__device__ inline void acc8(float* a, const uint4 v) {
  a[0] += bflo(v.x); a[1] += bfhi(v.x);
  a[2] += bflo(v.y); a[3] += bfhi(v.y);
  a[4] += bflo(v.z); a[5] += bfhi(v.z);
  a[6] += bflo(v.w); a[7] += bfhi(v.w);
}

// gather-accumulate one node's in-edges (8 bf16 feats @ fo) into acc[8]
__device__ inline void gather_node(const int* __restrict__ esrc,
                                   const unsigned short* __restrict__ Y,
                                   int beg, int end, int fo, float* acc) {
  int e = beg;
  for (; e < end && (e & 3); ++e) {
    const uint4 v = *(const uint4*)(Y + (size_t)esrc[e] * 128 + fo);
    acc8(acc, v);
  }
  for (; e + 8 <= end; e += 8) {  // 8 gathers in flight
    const int4 s0 = *(const int4*)(esrc + e);
    const int4 s1 = *(const int4*)(esrc + e + 4);
    const uint4 v0 = *(const uint4*)(Y + (size_t)s0.x * 128 + fo);
    const uint4 v1 = *(const uint4*)(Y + (size_t)s0.y * 128 + fo);
    const uint4 v2 = *(const uint4*)(Y + (size_t)s0.z * 128 + fo);
    const uint4 v3 = *(const uint4*)(Y + (size_t)s0.w * 128 + fo);
    const uint4 v4 = *(const uint4*)(Y + (size_t)s1.x * 128 + fo);
    const uint4 v5 = *(const uint4*)(Y + (size_t)s1.y * 128 + fo);
    const uint4 v6 = *(const uint4*)(Y + (size_t)s1.z * 128 + fo);
    const uint4 v7 = *(const uint4*)(Y + (size_t)s1.w * 128 + fo);
    acc8(acc, v0); acc8(acc, v1); acc8(acc, v2); acc8(acc, v3);
    acc8(acc, v4); acc8(acc, v5); acc8(acc, v6); acc8(acc, v7);
  }
  if (e + 4 <= end) {
    const int4 s0 = *(const int4*)(esrc + e);
    const uint4 v0 = *(const uint4*)(Y + (size_t)s0.x * 128 + fo);
    const uint4 v1 = *(const uint4*)(Y + (size_t)s0.y * 128 + fo);
    const uint4 v2 = *(const uint4*)(Y + (size_t)s0.z * 128 + fo);
    const uint4 v3 = *(const uint4*)(Y + (size_t)s0.w * 128 + fo);
    acc8(acc, v0); acc8(acc, v1); acc8(acc, v2); acc8(acc, v3);
    e += 4;
  }
  for (; e < end; ++e) {
    const uint4 v = *(const uint4*)(Y + (size_t)esrc[e] * 128 + fo);
    acc8(acc, v);
  }
}

// ---- P1: partition edges into fixed-capacity buckets ----------------------
// Two passes over (L2-hot) src/dst with int4 loads; LDS holds only the
// histograms/cursors (8KB). outS: src&255 ; outD: (dst&255)<<24 | src.
__global__ __launch_bounds__(256) void k_part(const int* __restrict__ src,
                                              const int* __restrict__ dst,
                                              int* __restrict__ curS,
                                              int* __restrict__ curD,
                                              unsigned char* __restrict__ outS,
                                              unsigned int* __restrict__ outD,
                                              int E, int NB) {
  __shared__ int hS[NBMAX];  // 4KB
  __shared__ int hD[NBMAX];  // 4KB
  const int t = threadIdx.x;
  for (int i = t; i < NB; i += 256) { hS[i] = 0; hD[i] = 0; }
  __syncthreads();
  const int e0 = blockIdx.x * EPB;
  #pragma unroll
  for (int i = 0; i < EPB / 1024; ++i) {
    const int e = e0 + (i * 256 + t) * 4;
    if (e + 3 < E) {
      const int4 s4 = *(const int4*)(src + e);
      const int4 d4 = *(const int4*)(dst + e);
      atomicAdd(&hS[s4.x >> 8], 1); atomicAdd(&hS[s4.y >> 8], 1);
      atomicAdd(&hS[s4.z >> 8], 1); atomicAdd(&hS[s4.w >> 8], 1);
      atomicAdd(&hD[d4.x >> 8], 1); atomicAdd(&hD[d4.y >> 8], 1);
      atomicAdd(&hD[d4.z >> 8], 1); atomicAdd(&hD[d4.w >> 8], 1);
    } else {
      for (int j = 0; j < 4; ++j) {
        if (e + j < E) {
          atomicAdd(&hS[src[e + j] >> 8], 1);
          atomicAdd(&hD[dst[e + j] >> 8], 1);
        }
      }
    }
  }
  __syncthreads();
  for (int i = t; i < NB; i += 256) {  // reserve chunks; hS/hD become cursors
    int c = hS[i];
    hS[i] = c ? atomicAdd(&curS[i], c) : 0;
    c = hD[i];
    hD[i] = c ? atomicAdd(&curD[i], c) : 0;
  }
  __syncthreads();
  #pragma unroll
  for (int i = 0; i < EPB / 1024; ++i) {
    const int e = e0 + (i * 256 + t) * 4;
    if (e + 3 < E) {
      const int4 s4 = *(const int4*)(src + e);
      const int4 d4 = *(const int4*)(dst + e);
      const int sv[4] = {s4.x, s4.y, s4.z, s4.w};
      const int dv[4] = {d4.x, d4.y, d4.z, d4.w};
      #pragma unroll
      for (int j = 0; j < 4; ++j) {
        int p = atomicAdd(&hS[sv[j] >> 8], 1);
        if (p < CAP)
          outS[(size_t)(sv[j] >> 8) * CAP + p] = (unsigned char)(sv[j] & 255);
        p = atomicAdd(&hD[dv[j] >> 8], 1);
        if (p < CAP)
          outD[(size_t)(dv[j] >> 8) * CAP + p] =
              ((unsigned)(dv[j] & 255) << 24) | (unsigned)sv[j];
      }
    } else {
      for (int j = 0; j < 4; ++j) {
        if (e + j < E) {
          const int sv = src[e + j], dv = dst[e + j];
          int p = atomicAdd(&hS[sv >> 8], 1);
          if (p < CAP)
            outS[(size_t)(sv >> 8) * CAP + p] = (unsigned char)(sv & 255);
          p = atomicAdd(&hD[dv >> 8], 1);
          if (p < CAP)
            outD[(size_t)(dv >> 8) * CAP + p] =
                ((unsigned)(dv & 255) << 24) | (unsigned)sv;
        }
      }
    }
  }
}

// ---- merged prep ------------------------------------------------------------
// [0,NB): CSR build with 2-level sort key (dstLocal*16 + srcRange) + cD;
// [NB,2NB): out-deg+cS ; gstart ; gsum=0 ; W split/pack.
// Sorting each node's list by src-range (16 ranges x 8192 rows) aligns the
// concurrent blocks' gather windows -> L2-resident src working set.
// W frag order: idx = ((kc*8+nb)*64 + lane)*8 + i  <-  W[k][n],
// k = kc*32 + (lane>>4)*8 + i, n = nb*16 + (lane&15). W2 frags at +16384.
__global__ __launch_bounds__(256) void k_prep(
    const unsigned int* __restrict__ outD, const int* __restrict__ curD,
    int2* __restrict__ rng, int* __restrict__ esrc, float* __restrict__ cD,
    const unsigned char* __restrict__ outS, const int* __restrict__ curS,
    float* __restrict__ cS, const int* __restrict__ gid,
    int* __restrict__ gstart, float* __restrict__ gsum,
    const float* __restrict__ W1, const float* __restrict__ W2,
    unsigned short* __restrict__ Whi, unsigned short* __restrict__ Wlo,
    int N, int NB, int G, int nbN, int nbG) {
  __shared__ int hist[4096];  // 16KB: per (dstLocal, srcRange) counts -> scan
  __shared__ int scn[256];
  const int b = blockIdx.x;
  const int t = threadIdx.x;

  if (b < NB) {  // ---- CSR build (src-range-sorted) + in-degree + cD ----
    const int beg = b * CAP;
    const int cnt = min(curD[b], CAP);
    #pragma unroll
    for (int i = 0; i < 16; ++i) hist[t * 16 + i] = 0;
    __syncthreads();
    for (int e = t; e < cnt; e += 256) {
      const unsigned w = outD[beg + e];
      const int key = (int)(w >> 24) * 16 + (int)((w & 0x1FFFFu) >> 13);
      atomicAdd(&hist[key], 1);
    }
    __syncthreads();
    // exclusive scan over the 4096 flattened keys (16/thread serial + block)
    int run = 0;
    int loc[16];
    #pragma unroll
    for (int i = 0; i < 16; ++i) { loc[i] = run; run += hist[t * 16 + i]; }
    scn[t] = run;
    __syncthreads();
    #pragma unroll
    for (int o = 1; o < 256; o <<= 1) {
      int u = (t >= o) ? scn[t - o] : 0;
      __syncthreads();
      scn[t] += u;
      __syncthreads();
    }
    const int texcl = scn[t] - run;
    #pragma unroll
    for (int i = 0; i < 16; ++i) hist[t * 16 + i] = loc[i] + texcl;
    __syncthreads();
    // per-node boundaries (node-local d = t): [hist[d*16], hist[(d+1)*16])
    const int start = hist[t * 16];
    const int dnext = (t == 255) ? cnt : hist[(t + 1) * 16];
    const int deg = dnext - start;
    const int node = b * RANGE + t;
    if (node < N) {
      cD[node] = rsqrtf((float)(deg > 1 ? deg : 1));
      rng[node] = make_int2(beg + start, beg + start + deg);
    }
    __syncthreads();  // boundary reads done before scatter mutates hist
    for (int e = t; e < cnt; e += 256) {
      const unsigned w = outD[beg + e];
      const int key = (int)(w >> 24) * 16 + (int)((w & 0x1FFFFu) >> 13);
      const int pos = beg + atomicAdd(&hist[key], 1);
      esrc[pos] = (int)(w & 0x1FFFFu);
    }
  } else if (b < 2 * NB) {  // ---- out-degree -> cS ----
    const int bb = b - NB;
    const int beg = bb * CAP;
    const int cnt = min(curS[bb], CAP);
    hist[t] = 0;
    __syncthreads();
    for (int e = t; e < cnt; e += 256)
      atomicAdd(&hist[outS[beg + e]], 1);
    __syncthreads();
    const int node = bb * RANGE + t;
    if (node < N) cS[node] = rsqrtf((float)(hist[t] > 1 ? hist[t] : 1));
  } else if (b < 2 * NB + nbN) {  // ---- graph starts from sorted gid ----
    const int i = (b - 2 * NB) * 256 + t;
    if (i < N) {
      const int g = gid[i];
      if (i == 0) {
        for (int q = 0; q <= g; ++q) gstart[q] = 0;
      } else {
        const int gp = gid[i - 1];
        for (int q = gp + 1; q <= g; ++q) gstart[q] = i;
      }
      if (i == N - 1) {
        for (int q = g + 1; q <= G; ++q) gstart[q] = N;
      }
    }
  } else if (b < 2 * NB + nbN + nbG) {  // ---- zero gsum ----
    const int i = (b - 2 * NB - nbN) * 256 + t;
    if (i < G) gsum[i] = 0.f;
  } else {  // ---- W split/pack ----
    const int g = (b - 2 * NB - nbN - nbG) * 256 + t;  // 0..32767
    const float* W = (g < 16384) ? W1 : W2;
    const int idx = g & 16383;
    const int i = idx & 7;
    const int l = (idx >> 3) & 63;
    const int nb = (idx >> 9) & 7;
    const int kc = idx >> 12;
    const int k = kc * 32 + ((l >> 4) << 3) + i;
    const int n = (nb << 4) + (l & 15);
    const float v = W[k * 128 + n];
    const unsigned short hi = f2bf(v);
    Whi[g] = hi;
    Wlo[g] = f2bf(v - bf2f(hi));
  }
}

// ---- MFMA GEMM: Y[N,128](bf16) = transform(X) @ W, split-bf16 -------------
// MODE 0: A'[r][k] = Xf[r][k] * cS[r]                      (fp32 input)
// MODE 1: A'[r][k] = relu(Xb[r][k]*cD[r] + bias[k]) * cS[r] (bf16 input)
// 4 waves/block, 16 rows/wave, no LDS. 96 MFMAs (16x16x32 bf16) per wave.
template <int MODE>
__global__ __launch_bounds__(256) void k_mgemm(const float* __restrict__ Xf,
                                               const unsigned short* __restrict__ Xb,
                                               const unsigned short* __restrict__ Whi,
                                               const unsigned short* __restrict__ Wlo,
                                               const float* __restrict__ cS,
                                               const float* __restrict__ cD,
                                               const float* __restrict__ bias,
                                               unsigned short* __restrict__ Y,
                                               int N) {
  const int t = threadIdx.x;
  const int wv = t >> 6;
  const int l = t & 63;
  const int lm = l & 15;
  const int lg = l >> 4;
  const int row0 = (blockIdx.x * 4 + wv) * 16;
  const int row = row0 + lm;
  const bool rv = row < N;
  const int rc = rv ? row : 0;
  const float csr = rv ? cS[rc] : 0.f;  // 0 -> A row = 0
  const float cdr = (MODE == 1) ? (rv ? cD[rc] : 0.f) : 0.f;

  facc4 acc[8];
  #pragma unroll
  for (int nb = 0; nb < 8; ++nb) acc[nb] = (facc4){0.f, 0.f, 0.f, 0.f};

  #pragma unroll
  for (int kc = 0; kc < 4; ++kc) {
    const int k0 = kc * 32 + (lg << 3);
    float a[8];
    if constexpr (MODE == 0) {
      const float4 x0 = *(const float4*)(Xf + (size_t)rc * 128 + k0);
      const float4 x1 = *(const float4*)(Xf + (size_t)rc * 128 + k0 + 4);
      a[0] = x0.x; a[1] = x0.y; a[2] = x0.z; a[3] = x0.w;
      a[4] = x1.x; a[5] = x1.y; a[6] = x1.z; a[7] = x1.w;
      #pragma unroll
      for (int i = 0; i < 8; ++i) a[i] *= csr;
    } else {
      const uint4 xb = *(const uint4*)(Xb + (size_t)rc * 128 + k0);
      a[0] = bflo(xb.x); a[1] = bfhi(xb.x);
      a[2] = bflo(xb.y); a[3] = bfhi(xb.y);
      a[4] = bflo(xb.z); a[5] = bfhi(xb.z);
      a[6] = bflo(xb.w); a[7] = bfhi(xb.w);
      const float4 b0 = *(const float4*)(bias + k0);
      const float4 b1 = *(const float4*)(bias + k0 + 4);
      const float bb[8] = {b0.x, b0.y, b0.z, b0.w, b1.x, b1.y, b1.z, b1.w};
      #pragma unroll
      for (int i = 0; i < 8; ++i)
        a[i] = fmaxf(fmaf(a[i], cdr, bb[i]), 0.f) * csr;
    }
    bfrag8 ah, al;
    #pragma unroll
    for (int i = 0; i < 8; ++i) {
      const unsigned short hh = f2bf(a[i]);
      ah[i] = (short)hh;
      al[i] = (short)f2bf(a[i] - bf2f(hh));
    }
    const size_t kb = ((size_t)kc * 8) * 512 + (size_t)l * 8;
    #pragma unroll
    for (int nb = 0; nb < 8; ++nb) {
      const bfrag8 bh = *(const bfrag8*)(Whi + kb + (size_t)nb * 512);
      const bfrag8 bl = *(const bfrag8*)(Wlo + kb + (size_t)nb * 512);
      acc[nb] = __builtin_amdgcn_mfma_f32_16x16x32_bf16(ah, bh, acc[nb], 0, 0, 0);
      acc[nb] = __builtin_amdgcn_mfma_f32_16x16x32_bf16(ah, bl, acc[nb], 0, 0, 0);
      acc[nb] = __builtin_amdgcn_mfma_f32_16x16x32_bf16(al, bh, acc[nb], 0, 0, 0);
    }
  }

  // C/D layout: col = lane&15, row_in_tile = (lane>>4)*4 + j
  #pragma unroll
  for (int j = 0; j < 4; ++j) {
    const int r = row0 + (lg << 2) + j;
    if (r < N) {
      #pragma unroll
      for (int nb = 0; nb < 8; ++nb)
        Y[(size_t)r * 128 + (nb << 4) + lm] = f2bf(acc[nb][j]);
    }
  }
}

// ---- CSR SpMM over bf16 Y, fp32 accumulate ---------------------------------
// 16 lanes/node (uint4 = 16B/lane), 8-deep gather unroll. One node-group per
// block (r11 structure — measured best).
// MODE 0: aggb[d] = bf16(sum). MODE 1: fused readout (dot + graph sums).
template <int MODE>
__global__ __launch_bounds__(256) void k_spmm(const int2* __restrict__ rng,
                                              const int* __restrict__ esrc,
                                              const unsigned short* __restrict__ Y,
                                              unsigned short* __restrict__ aggb,
                                              const float* __restrict__ cD,
                                              const float* __restrict__ b2,
                                              const float* __restrict__ fcw,
                                              const int* __restrict__ gid,
                                              float* __restrict__ gsum, int N) {
  __shared__ float sVal[16];
  __shared__ int sGid[16];
  const int t = threadIdx.x;
  const int lane = t & 15;   // 16 lanes per node
  const int grp = t >> 4;    // 0..15
  const int node = blockIdx.x * 16 + grp;
  const int fo = lane * 8;   // feature offset (8 elems = 16B per lane)

  float acc[8] = {0.f, 0.f, 0.f, 0.f, 0.f, 0.f, 0.f, 0.f};
  if (node < N) {
    const int2 be = rng[node];
    gather_node(esrc, Y, be.x, be.y, fo, acc);
  }

  if constexpr (MODE == 0) {
    if (node < N) {
      uint4 w;
      w.x = (unsigned)f2bf(acc[0]) | ((unsigned)f2bf(acc[1]) << 16);
      w.y = (unsigned)f2bf(acc[2]) | ((unsigned)f2bf(acc[3]) << 16);
      w.z = (unsigned)f2bf(acc[4]) | ((unsigned)f2bf(acc[5]) << 16);
      w.w = (unsigned)f2bf(acc[6]) | ((unsigned)f2bf(acc[7]) << 16);
      *(uint4*)(aggb + (size_t)node * 128 + fo) = w;
    }
  } else {
    float s = 0.f;
    if (node < N) {
      const float c = cD[node];
      const float4 bA = *(const float4*)(b2 + fo);
      const float4 bB = *(const float4*)(b2 + fo + 4);
      const float4 wA = *(const float4*)(fcw + fo);
      const float4 wB = *(const float4*)(fcw + fo + 4);
      s += fmaxf(fmaf(acc[0], c, bA.x), 0.f) * wA.x;
      s += fmaxf(fmaf(acc[1], c, bA.y), 0.f) * wA.y;
      s += fmaxf(fmaf(acc[2], c, bA.z), 0.f) * wA.z;
      s += fmaxf(fmaf(acc[3], c, bA.w), 0.f) * wA.w;
      s += fmaxf(fmaf(acc[4], c, bB.x), 0.f) * wB.x;
      s += fmaxf(fmaf(acc[5], c, bB.y), 0.f) * wB.y;
      s += fmaxf(fmaf(acc[6], c, bB.z), 0.f) * wB.z;
      s += fmaxf(fmaf(acc[7], c, bB.w), 0.f) * wB.w;
    }
    #pragma unroll
    for (int o = 8; o > 0; o >>= 1) s += __shfl_down(s, o, 16);
    if (lane == 0) {
      sVal[grp] = (node < N) ? s : 0.f;
      sGid[grp] = (node < N) ? gid[node] : -1;
    }
    __syncthreads();
    if (t == 0) {  // run-combine 16 sorted entries -> few atomics/block
      int cg = -1;
      float cs = 0.f;
      #pragma unroll
      for (int k = 0; k < 16; ++k) {
        const int g = sGid[k];
        if (g < 0) continue;
        if (g == cg) {
          cs += sVal[k];
        } else {
          if (cg >= 0) atomicAdd(&gsum[cg], cs);
          cg = g;
          cs = sVal[k];
        }
      }
      if (cg >= 0) atomicAdd(&gsum[cg], cs);
    }
  }
}

__global__ __launch_bounds__(256) void k_final(const float* __restrict__ gsum,
                                               const int* __restrict__ gstart,
                                               const float* __restrict__ fcb,
                                               float* __restrict__ out, int G) {
  const int g = blockIdx.x * 256 + threadIdx.x;
  if (g < G) {
    const int cnt = gstart[g + 1] - gstart[g];
    out[g] = gsum[g] / fmaxf((float)cnt, 1.f) + fcb[0];
  }
}

// ---------------------------------------------------------------------------
extern "C" void kernel_launch(void* const* d_in, const int* in_sizes, int n_in,
                              void* d_out, int out_size, void* d_ws, size_t ws_size,
                              hipStream_t stream) {
  const float* h   = (const float*)d_in[0];
  const int*   src = (const int*)d_in[1];
  const int*   dst = (const int*)d_in[2];
  const int*   gid = (const int*)d_in[3];
  const float* W1  = (const float*)d_in[5];
  const float* b1  = (const float*)d_in[6];
  const float* W2  = (const float*)d_in[7];
  const float* b2  = (const float*)d_in[8];
  const float* fcw = (const float*)d_in[9];
  const float* fcb = (const float*)d_in[10];
  float* out = (float*)d_out;

  const int N = in_sizes[0] / 128;
  const int E = in_sizes[1];
  const int G = out_size;
  const int NB = (N + RANGE - 1) / RANGE;

  char* base = (char*)d_ws;
  size_t off = 0;
  auto alloc = [&](size_t bytes) -> void* {
    void* p = base + off;
    off += (bytes + 1023) & ~(size_t)1023;
    return p;
  };
  unsigned short* Y    = (unsigned short*)alloc((size_t)N * 128 * 2);  // 25.6MB
  unsigned short* aggb = (unsigned short*)alloc((size_t)N * 128 * 2);  // 25.6MB
  // padded bucket arrays alias into aggb (dead before spmm<0> writes aggb)
  unsigned int*  outD = (unsigned int*)aggb;                         // NB*CAP*4
  unsigned char* outS = (unsigned char*)aggb + (size_t)NB * CAP * 4; // NB*CAP
  float* cS     = (float*)alloc((size_t)N * 4);
  float* cD     = (float*)alloc((size_t)N * 4);
  int2*  rng    = (int2*)alloc((size_t)N * 8);
  int*   esrc   = (int*)alloc((size_t)NB * CAP * 4);   // 8MB padded
  int*   cur    = (int*)alloc((size_t)2 * NBMAX * 4);  // curS | curD
  float* gsum   = (float*)alloc((size_t)G * 4);
  int*   gstart = (int*)alloc((size_t)(G + 1) * 4);
  unsigned short* Whi = (unsigned short*)alloc(32768 * 2);  // W1 | W2 frags
  unsigned short* Wlo = (unsigned short*)alloc(32768 * 2);
  (void)ws_size; (void)n_in;

  hipMemsetAsync(cur, 0, (size_t)2 * NBMAX * 4, stream);

  const int nbP = (E + EPB - 1) / EPB;
  const int nbN = (N + 255) / 256;
  const int nbG = (G + 255) / 256;
  k_part<<<nbP, 256, 0, stream>>>(src, dst, cur, cur + NBMAX, outS, outD, E, NB);
  k_prep<<<2 * NB + nbN + nbG + 128, 256, 0, stream>>>(
      outD, cur + NBMAX, rng, esrc, cD, outS, cur, cS, gid, gstart, gsum,
      W1, W2, Whi, Wlo, N, NB, G, nbN, nbG);

  const int nbM = (N + 63) / 64;   // 64 rows per block (4 waves x 16)
  const int nbS = (N + 15) / 16;   // 16 nodes per block (r11 structure)
  // layer 1: Y = (h * cS) @ W1 ; aggb = bf16(SpMM(Y))
  k_mgemm<0><<<nbM, 256, 0, stream>>>(h, (const unsigned short*)nullptr, Whi,
                                      Wlo, cS, cD, b1, Y, N);
  k_spmm<0><<<nbS, 256, 0, stream>>>(rng, esrc, Y, aggb, cD, b2, fcw, gid,
                                     gsum, N);
  // layer 2: Y = (relu(aggb*cD + b1) * cS) @ W2  (in-place Y reuse) ; readout
  k_mgemm<1><<<nbM, 256, 0, stream>>>((const float*)nullptr, aggb, Whi + 16384,
                                      Wlo + 16384, cS, cD, b1, Y, N);
  k_spmm<1><<<nbS, 256, 0, stream>>>(rng, esrc, Y, aggb, cD, b2, fcw, gid,
                                     gsum, N);
  k_final<<<nbG, 256, 0, stream>>>(gsum, gstart, fcb, out, G);
}

// Round 14
// 228.406 us; speedup vs baseline: 1.0845x; 1.0126x over previous
//
#include <hip/hip_runtime.h>

// ---------------------------------------------------------------------------
// GCN regressor: 2x GraphConv(norm='both') + ReLU, per-graph mean, linear.
// N=100000 nodes, E=1.6M edges, F=HID=128, G=1024 graphs.
//
// Round 14: SpMM restructured to ONE NODE PER WAVE (64 lanes x 4B = 256B row;
// edge loop is wave-uniform -> scalar esrc loads, ZERO divergence). The old
// 16-lane-group layout burned ~22% of issue slots on masked lanes (wave time
// = max of 4 node degrees). MODE1 readout: per-wave shfl reduce + 1 atomic
// from lane0; node order stride-permuted (x9973 mod N) to decluster same-gid
// atomics (r2 lesson). No barriers. Everything else = r13 (231.3us best).
// ---------------------------------------------------------------------------

#define RANGE 256   // nodes per bucket (power of 2; local id fits 8 bits)
#define NBMAX 1024  // max buckets supported (N <= 262144)
#define EPB 4096    // edges per partition block
#define CAP 5120    // padded slots per bucket (mean 4092, sigma 64 -> 16 sigma)

typedef __attribute__((ext_vector_type(4))) float facc4;
typedef __attribute__((ext_vector_type(8))) short bfrag8;

__device__ inline unsigned short f2bf(float x) {  // RNE, finite inputs
  unsigned u = __float_as_uint(x);
  u += 0x7FFFu + ((u >> 16) & 1u);
  return (unsigned short)(u >> 16);
}
__device__ inline float bf2f(unsigned short b) {
  return __uint_as_float((unsigned)b << 16);
}
__device__ inline float bflo(unsigned u) { return __uint_as_float(u << 16); }
__device__ inline float bfhi(unsigned u) { return __uint_as_float(u & 0xFFFF0000u); }

// ---- P1: partition edges into fixed-capacity buckets ----------------------
__global__ __launch_bounds__(256) void k_part(const int* __restrict__ src,
                                              const int* __restrict__ dst,
                                              int* __restrict__ curS,
                                              int* __restrict__ curD,
                                              unsigned char* __restrict__ outS,
                                              unsigned int* __restrict__ outD,
                                              int E, int NB) {
  __shared__ int hS[NBMAX];  // 4KB
  __shared__ int hD[NBMAX];  // 4KB
  const int t = threadIdx.x;
  for (int i = t; i < NB; i += 256) { hS[i] = 0; hD[i] = 0; }
  __syncthreads();
  const int e0 = blockIdx.x * EPB;
  #pragma unroll
  for (int i = 0; i < EPB / 1024; ++i) {
    const int e = e0 + (i * 256 + t) * 4;
    if (e + 3 < E) {
      const int4 s4 = *(const int4*)(src + e);
      const int4 d4 = *(const int4*)(dst + e);
      atomicAdd(&hS[s4.x >> 8], 1); atomicAdd(&hS[s4.y >> 8], 1);
      atomicAdd(&hS[s4.z >> 8], 1); atomicAdd(&hS[s4.w >> 8], 1);
      atomicAdd(&hD[d4.x >> 8], 1); atomicAdd(&hD[d4.y >> 8], 1);
      atomicAdd(&hD[d4.z >> 8], 1); atomicAdd(&hD[d4.w >> 8], 1);
    } else {
      for (int j = 0; j < 4; ++j) {
        if (e + j < E) {
          atomicAdd(&hS[src[e + j] >> 8], 1);
          atomicAdd(&hD[dst[e + j] >> 8], 1);
        }
      }
    }
  }
  __syncthreads();
  for (int i = t; i < NB; i += 256) {  // reserve chunks; hS/hD become cursors
    int c = hS[i];
    hS[i] = c ? atomicAdd(&curS[i], c) : 0;
    c = hD[i];
    hD[i] = c ? atomicAdd(&curD[i], c) : 0;
  }
  __syncthreads();
  #pragma unroll
  for (int i = 0; i < EPB / 1024; ++i) {
    const int e = e0 + (i * 256 + t) * 4;
    if (e + 3 < E) {
      const int4 s4 = *(const int4*)(src + e);
      const int4 d4 = *(const int4*)(dst + e);
      const int sv[4] = {s4.x, s4.y, s4.z, s4.w};
      const int dv[4] = {d4.x, d4.y, d4.z, d4.w};
      #pragma unroll
      for (int j = 0; j < 4; ++j) {
        int p = atomicAdd(&hS[sv[j] >> 8], 1);
        if (p < CAP)
          outS[(size_t)(sv[j] >> 8) * CAP + p] = (unsigned char)(sv[j] & 255);
        p = atomicAdd(&hD[dv[j] >> 8], 1);
        if (p < CAP)
          outD[(size_t)(dv[j] >> 8) * CAP + p] =
              ((unsigned)(dv[j] & 255) << 24) | (unsigned)sv[j];
      }
    } else {
      for (int j = 0; j < 4; ++j) {
        if (e + j < E) {
          const int sv = src[e + j], dv = dst[e + j];
          int p = atomicAdd(&hS[sv >> 8], 1);
          if (p < CAP)
            outS[(size_t)(sv >> 8) * CAP + p] = (unsigned char)(sv & 255);
          p = atomicAdd(&hD[dv >> 8], 1);
          if (p < CAP)
            outD[(size_t)(dv >> 8) * CAP + p] =
                ((unsigned)(dv & 255) << 24) | (unsigned)sv;
        }
      }
    }
  }
}

// ---- merged prep: CSR (src-range-sorted) + cD ; out-deg + cS ; gstart ;
//      gsum=0 ; W split/pack. -------------------------------------------------
__global__ __launch_bounds__(256) void k_prep(
    const unsigned int* __restrict__ outD, const int* __restrict__ curD,
    int2* __restrict__ rng, int* __restrict__ esrc, float* __restrict__ cD,
    const unsigned char* __restrict__ outS, const int* __restrict__ curS,
    float* __restrict__ cS, const int* __restrict__ gid,
    int* __restrict__ gstart, float* __restrict__ gsum,
    const float* __restrict__ W1, const float* __restrict__ W2,
    unsigned short* __restrict__ Whi, unsigned short* __restrict__ Wlo,
    int N, int NB, int G, int nbN, int nbG) {
  __shared__ int hist[4096];  // 16KB
  __shared__ int scn[256];
  const int b = blockIdx.x;
  const int t = threadIdx.x;

  if (b < NB) {  // ---- CSR build (src-range-sorted) + in-degree + cD ----
    const int beg = b * CAP;
    const int cnt = min(curD[b], CAP);
    #pragma unroll
    for (int i = 0; i < 16; ++i) hist[t * 16 + i] = 0;
    __syncthreads();
    for (int e = t; e < cnt; e += 256) {
      const unsigned w = outD[beg + e];
      const int key = (int)(w >> 24) * 16 + (int)((w & 0x1FFFFu) >> 13);
      atomicAdd(&hist[key], 1);
    }
    __syncthreads();
    int run = 0;
    int loc[16];
    #pragma unroll
    for (int i = 0; i < 16; ++i) { loc[i] = run; run += hist[t * 16 + i]; }
    scn[t] = run;
    __syncthreads();
    #pragma unroll
    for (int o = 1; o < 256; o <<= 1) {
      int u = (t >= o) ? scn[t - o] : 0;
      __syncthreads();
      scn[t] += u;
      __syncthreads();
    }
    const int texcl = scn[t] - run;
    #pragma unroll
    for (int i = 0; i < 16; ++i) hist[t * 16 + i] = loc[i] + texcl;
    __syncthreads();
    const int start = hist[t * 16];
    const int dnext = (t == 255) ? cnt : hist[(t + 1) * 16];
    const int deg = dnext - start;
    const int node = b * RANGE + t;
    if (node < N) {
      cD[node] = rsqrtf((float)(deg > 1 ? deg : 1));
      rng[node] = make_int2(beg + start, beg + start + deg);
    }
    __syncthreads();
    for (int e = t; e < cnt; e += 256) {
      const unsigned w = outD[beg + e];
      const int key = (int)(w >> 24) * 16 + (int)((w & 0x1FFFFu) >> 13);
      const int pos = beg + atomicAdd(&hist[key], 1);
      esrc[pos] = (int)(w & 0x1FFFFu);
    }
  } else if (b < 2 * NB) {  // ---- out-degree -> cS ----
    const int bb = b - NB;
    const int beg = bb * CAP;
    const int cnt = min(curS[bb], CAP);
    hist[t] = 0;
    __syncthreads();
    for (int e = t; e < cnt; e += 256)
      atomicAdd(&hist[outS[beg + e]], 1);
    __syncthreads();
    const int node = bb * RANGE + t;
    if (node < N) cS[node] = rsqrtf((float)(hist[t] > 1 ? hist[t] : 1));
  } else if (b < 2 * NB + nbN) {  // ---- graph starts from sorted gid ----
    const int i = (b - 2 * NB) * 256 + t;
    if (i < N) {
      const int g = gid[i];
      if (i == 0) {
        for (int q = 0; q <= g; ++q) gstart[q] = 0;
      } else {
        const int gp = gid[i - 1];
        for (int q = gp + 1; q <= g; ++q) gstart[q] = i;
      }
      if (i == N - 1) {
        for (int q = g + 1; q <= G; ++q) gstart[q] = N;
      }
    }
  } else if (b < 2 * NB + nbN + nbG) {  // ---- zero gsum ----
    const int i = (b - 2 * NB - nbN) * 256 + t;
    if (i < G) gsum[i] = 0.f;
  } else {  // ---- W split/pack ----
    const int g = (b - 2 * NB - nbN - nbG) * 256 + t;  // 0..32767
    const float* W = (g < 16384) ? W1 : W2;
    const int idx = g & 16383;
    const int i = idx & 7;
    const int l = (idx >> 3) & 63;
    const int nb = (idx >> 9) & 7;
    const int kc = idx >> 12;
    const int k = kc * 32 + ((l >> 4) << 3) + i;
    const int n = (nb << 4) + (l & 15);
    const float v = W[k * 128 + n];
    const unsigned short hi = f2bf(v);
    Whi[g] = hi;
    Wlo[g] = f2bf(v - bf2f(hi));
  }
}

// ---- MFMA GEMM: Y[N,128](bf16) = transform(X) @ W, split-bf16 -------------
template <int MODE>
__global__ __launch_bounds__(256) void k_mgemm(const float* __restrict__ Xf,
                                               const unsigned short* __restrict__ Xb,
                                               const unsigned short* __restrict__ Whi,
                                               const unsigned short* __restrict__ Wlo,
                                               const float* __restrict__ cS,
                                               const float* __restrict__ cD,
                                               const float* __restrict__ bias,
                                               unsigned short* __restrict__ Y,
                                               int N) {
  const int t = threadIdx.x;
  const int wv = t >> 6;
  const int l = t & 63;
  const int lm = l & 15;
  const int lg = l >> 4;
  const int row0 = (blockIdx.x * 4 + wv) * 16;
  const int row = row0 + lm;
  const bool rv = row < N;
  const int rc = rv ? row : 0;
  const float csr = rv ? cS[rc] : 0.f;  // 0 -> A row = 0
  const float cdr = (MODE == 1) ? (rv ? cD[rc] : 0.f) : 0.f;

  facc4 acc[8];
  #pragma unroll
  for (int nb = 0; nb < 8; ++nb) acc[nb] = (facc4){0.f, 0.f, 0.f, 0.f};

  #pragma unroll
  for (int kc = 0; kc < 4; ++kc) {
    const int k0 = kc * 32 + (lg << 3);
    float a[8];
    if constexpr (MODE == 0) {
      const float4 x0 = *(const float4*)(Xf + (size_t)rc * 128 + k0);
      const float4 x1 = *(const float4*)(Xf + (size_t)rc * 128 + k0 + 4);
      a[0] = x0.x; a[1] = x0.y; a[2] = x0.z; a[3] = x0.w;
      a[4] = x1.x; a[5] = x1.y; a[6] = x1.z; a[7] = x1.w;
      #pragma unroll
      for (int i = 0; i < 8; ++i) a[i] *= csr;
    } else {
      const uint4 xb = *(const uint4*)(Xb + (size_t)rc * 128 + k0);
      a[0] = bflo(xb.x); a[1] = bfhi(xb.x);
      a[2] = bflo(xb.y); a[3] = bfhi(xb.y);
      a[4] = bflo(xb.z); a[5] = bfhi(xb.z);
      a[6] = bflo(xb.w); a[7] = bfhi(xb.w);
      const float4 b0 = *(const float4*)(bias + k0);
      const float4 b1 = *(const float4*)(bias + k0 + 4);
      const float bb[8] = {b0.x, b0.y, b0.z, b0.w, b1.x, b1.y, b1.z, b1.w};
      #pragma unroll
      for (int i = 0; i < 8; ++i)
        a[i] = fmaxf(fmaf(a[i], cdr, bb[i]), 0.f) * csr;
    }
    bfrag8 ah, al;
    #pragma unroll
    for (int i = 0; i < 8; ++i) {
      const unsigned short hh = f2bf(a[i]);
      ah[i] = (short)hh;
      al[i] = (short)f2bf(a[i] - bf2f(hh));
    }
    const size_t kb = ((size_t)kc * 8) * 512 + (size_t)l * 8;
    #pragma unroll
    for (int nb = 0; nb < 8; ++nb) {
      const bfrag8 bh = *(const bfrag8*)(Whi + kb + (size_t)nb * 512);
      const bfrag8 bl = *(const bfrag8*)(Wlo + kb + (size_t)nb * 512);
      acc[nb] = __builtin_amdgcn_mfma_f32_16x16x32_bf16(ah, bh, acc[nb], 0, 0, 0);
      acc[nb] = __builtin_amdgcn_mfma_f32_16x16x32_bf16(ah, bl, acc[nb], 0, 0, 0);
      acc[nb] = __builtin_amdgcn_mfma_f32_16x16x32_bf16(al, bh, acc[nb], 0, 0, 0);
    }
  }

  #pragma unroll
  for (int j = 0; j < 4; ++j) {
    const int r = row0 + (lg << 2) + j;
    if (r < N) {
      #pragma unroll
      for (int nb = 0; nb < 8; ++nb)
        Y[(size_t)r * 128 + (nb << 4) + lm] = f2bf(acc[nb][j]);
    }
  }
}

// ---- CSR SpMM, ONE NODE PER WAVE -------------------------------------------
// 64 lanes x 4B (2 bf16 feats) cover the 256B row; edge loop is wave-uniform
// (scalar esrc loads, zero divergence). 8-deep unroll. No barriers.
// MODE 0: aggb[node] = bf16(sum), natural node order.
// MODE 1: readout; node order stride-permuted to decluster same-gid atomics.
template <int MODE>
__global__ __launch_bounds__(256) void k_spmm(const int2* __restrict__ rng,
                                              const int* __restrict__ esrc,
                                              const unsigned short* __restrict__ Y,
                                              unsigned short* __restrict__ aggb,
                                              const float* __restrict__ cD,
                                              const float* __restrict__ b2,
                                              const float* __restrict__ fcw,
                                              const int* __restrict__ gid,
                                              float* __restrict__ gsum,
                                              int N, int strideM) {
  const int t = threadIdx.x;
  const int lane = t & 63;
  const int widx = blockIdx.x * 4 + (t >> 6);
  if (widx >= N) return;  // wave-uniform
  int node;
  if constexpr (MODE == 1) {
    node = (int)(((long long)widx * strideM) % N);
  } else {
    node = widx;
  }
  node = __builtin_amdgcn_readfirstlane(node);
  const int2 be = rng[node];
  const int f0 = lane * 2;
  const unsigned short* __restrict__ Yf = Y + f0;

  float a0 = 0.f, a1 = 0.f;
  float b0 = 0.f, b1a = 0.f;  // second accumulator pair (ILP)
  int e = be.x;
  const int end = be.y;
  for (; e + 8 <= end; e += 8) {  // 8 rows in flight (scalar idx loads)
    const int s0 = esrc[e + 0];
    const int s1 = esrc[e + 1];
    const int s2 = esrc[e + 2];
    const int s3 = esrc[e + 3];
    const int s4 = esrc[e + 4];
    const int s5 = esrc[e + 5];
    const int s6 = esrc[e + 6];
    const int s7 = esrc[e + 7];
    const unsigned v0 = *(const unsigned*)(Yf + (size_t)s0 * 128);
    const unsigned v1 = *(const unsigned*)(Yf + (size_t)s1 * 128);
    const unsigned v2 = *(const unsigned*)(Yf + (size_t)s2 * 128);
    const unsigned v3 = *(const unsigned*)(Yf + (size_t)s3 * 128);
    const unsigned v4 = *(const unsigned*)(Yf + (size_t)s4 * 128);
    const unsigned v5 = *(const unsigned*)(Yf + (size_t)s5 * 128);
    const unsigned v6 = *(const unsigned*)(Yf + (size_t)s6 * 128);
    const unsigned v7 = *(const unsigned*)(Yf + (size_t)s7 * 128);
    a0 += bflo(v0); a1 += bfhi(v0);
    b0 += bflo(v1); b1a += bfhi(v1);
    a0 += bflo(v2); a1 += bfhi(v2);
    b0 += bflo(v3); b1a += bfhi(v3);
    a0 += bflo(v4); a1 += bfhi(v4);
    b0 += bflo(v5); b1a += bfhi(v5);
    a0 += bflo(v6); a1 += bfhi(v6);
    b0 += bflo(v7); b1a += bfhi(v7);
  }
  if (e + 4 <= end) {
    const int s0 = esrc[e + 0];
    const int s1 = esrc[e + 1];
    const int s2 = esrc[e + 2];
    const int s3 = esrc[e + 3];
    const unsigned v0 = *(const unsigned*)(Yf + (size_t)s0 * 128);
    const unsigned v1 = *(const unsigned*)(Yf + (size_t)s1 * 128);
    const unsigned v2 = *(const unsigned*)(Yf + (size_t)s2 * 128);
    const unsigned v3 = *(const unsigned*)(Yf + (size_t)s3 * 128);
    a0 += bflo(v0); a1 += bfhi(v0);
    b0 += bflo(v1); b1a += bfhi(v1);
    a0 += bflo(v2); a1 += bfhi(v2);
    b0 += bflo(v3); b1a += bfhi(v3);
    e += 4;
  }
  for (; e < end; ++e) {
    const unsigned v = *(const unsigned*)(Yf + (size_t)esrc[e] * 128);
    a0 += bflo(v); a1 += bfhi(v);
  }
  a0 += b0;
  a1 += b1a;

  if constexpr (MODE == 0) {
    const unsigned w = (unsigned)f2bf(a0) | ((unsigned)f2bf(a1) << 16);
    *(unsigned*)(aggb + (size_t)node * 128 + f0) = w;
  } else {
    const float c = cD[node];
    const float2 bb = *(const float2*)(b2 + f0);
    const float2 ww = *(const float2*)(fcw + f0);
    float s = fmaxf(fmaf(a0, c, bb.x), 0.f) * ww.x +
              fmaxf(fmaf(a1, c, bb.y), 0.f) * ww.y;
    #pragma unroll
    for (int o = 32; o > 0; o >>= 1) s += __shfl_down(s, o, 64);
    if (lane == 0) atomicAdd(&gsum[gid[node]], s);
  }
}

__global__ __launch_bounds__(256) void k_final(const float* __restrict__ gsum,
                                               const int* __restrict__ gstart,
                                               const float* __restrict__ fcb,
                                               float* __restrict__ out, int G) {
  const int g = blockIdx.x * 256 + threadIdx.x;
  if (g < G) {
    const int cnt = gstart[g + 1] - gstart[g];
    out[g] = gsum[g] / fmaxf((float)cnt, 1.f) + fcb[0];
  }
}

// ---------------------------------------------------------------------------
extern "C" void kernel_launch(void* const* d_in, const int* in_sizes, int n_in,
                              void* d_out, int out_size, void* d_ws, size_t ws_size,
                              hipStream_t stream) {
  const float* h   = (const float*)d_in[0];
  const int*   src = (const int*)d_in[1];
  const int*   dst = (const int*)d_in[2];
  const int*   gid = (const int*)d_in[3];
  const float* W1  = (const float*)d_in[5];
  const float* b1  = (const float*)d_in[6];
  const float* W2  = (const float*)d_in[7];
  const float* b2  = (const float*)d_in[8];
  const float* fcw = (const float*)d_in[9];
  const float* fcb = (const float*)d_in[10];
  float* out = (float*)d_out;

  const int N = in_sizes[0] / 128;
  const int E = in_sizes[1];
  const int G = out_size;
  const int NB = (N + RANGE - 1) / RANGE;
  const int strideM = (N % 9973) ? 9973 : 1;  // coprime permutation stride

  char* base = (char*)d_ws;
  size_t off = 0;
  auto alloc = [&](size_t bytes) -> void* {
    void* p = base + off;
    off += (bytes + 1023) & ~(size_t)1023;
    return p;
  };
  unsigned short* Y    = (unsigned short*)alloc((size_t)N * 128 * 2);  // 25.6MB
  unsigned short* aggb = (unsigned short*)alloc((size_t)N * 128 * 2);  // 25.6MB
  // padded bucket arrays alias into aggb (dead before spmm<0> writes aggb)
  unsigned int*  outD = (unsigned int*)aggb;                         // NB*CAP*4
  unsigned char* outS = (unsigned char*)aggb + (size_t)NB * CAP * 4; // NB*CAP
  float* cS     = (float*)alloc((size_t)N * 4);
  float* cD     = (float*)alloc((size_t)N * 4);
  int2*  rng    = (int2*)alloc((size_t)N * 8);
  int*   esrc   = (int*)alloc((size_t)NB * CAP * 4);   // 8MB padded
  int*   cur    = (int*)alloc((size_t)2 * NBMAX * 4);  // curS | curD
  float* gsum   = (float*)alloc((size_t)G * 4);
  int*   gstart = (int*)alloc((size_t)(G + 1) * 4);
  unsigned short* Whi = (unsigned short*)alloc(32768 * 2);  // W1 | W2 frags
  unsigned short* Wlo = (unsigned short*)alloc(32768 * 2);
  (void)ws_size; (void)n_in;

  hipMemsetAsync(cur, 0, (size_t)2 * NBMAX * 4, stream);

  const int nbP = (E + EPB - 1) / EPB;
  const int nbN = (N + 255) / 256;
  const int nbG = (G + 255) / 256;
  k_part<<<nbP, 256, 0, stream>>>(src, dst, cur, cur + NBMAX, outS, outD, E, NB);
  k_prep<<<2 * NB + nbN + nbG + 128, 256, 0, stream>>>(
      outD, cur + NBMAX, rng, esrc, cD, outS, cur, cS, gid, gstart, gsum,
      W1, W2, Whi, Wlo, N, NB, G, nbN, nbG);

  const int nbM = (N + 63) / 64;   // 64 rows per block (4 waves x 16)
  const int nbS = (N + 3) / 4;     // 4 nodes (waves) per block
  // layer 1: Y = (h * cS) @ W1 ; aggb = bf16(SpMM(Y))
  k_mgemm<0><<<nbM, 256, 0, stream>>>(h, (const unsigned short*)nullptr, Whi,
                                      Wlo, cS, cD, b1, Y, N);
  k_spmm<0><<<nbS, 256, 0, stream>>>(rng, esrc, Y, aggb, cD, b2, fcw, gid,
                                     gsum, N, strideM);
  // layer 2: Y = (relu(aggb*cD + b1) * cS) @ W2  (in-place Y reuse) ; readout
  k_mgemm<1><<<nbM, 256, 0, stream>>>((const float*)nullptr, aggb, Whi + 16384,
                                      Wlo + 16384, cS, cD, b1, Y, N);
  k_spmm<1><<<nbS, 256, 0, stream>>>(rng, esrc, Y, aggb, cD, b2, fcw, gid,
                                     gsum, N, strideM);
  k_final<<<nbG, 256, 0, stream>>>(gsum, gstart, fcb, out, G);
}